// Round 7
// baseline (127.495 us; speedup 1.0000x reference)
//
#include <hip/hip_runtime.h>

#define BB 2
#define NN 768
#define FF 128
#define HH 128
#define TS 32
#define LST 68                       // LDS row stride (floats): 272B rows, 16B-aligned, <=2-way banks
#define NT (NN / TS)                 // 24 tiles per dim
#define NPAIR (NT * (NT + 1) / 2)    // 300 upper-triangular tile pairs
#define THR 4e-3f

// ---- exact f64 slow path: recompute gram from global Xc + f64 MLP --------
// Same values/fma order as the original always-f64 kernel; executed only in a
// cold branch (|m32| < THR, ~1e-4 of edges). Fully inlined: no call ABI/spills.
__device__ __forceinline__
double edge_exact_f64(const double* __restrict__ Xc, const double* __restrict__ wpack,
                      int b, int i, int j, double init) {
    const double* xi0 = Xc + ((size_t)(b * 2 + 0) * NN + i) * 64;
    const double* xj0 = Xc + ((size_t)(b * 2 + 0) * NN + j) * 64;
    const double* xi1 = Xc + ((size_t)(b * 2 + 1) * NN + i) * 64;
    const double* xj1 = Xc + ((size_t)(b * 2 + 1) * NN + j) * 64;
    double p0 = 0.0, p1 = 0.0;
#pragma unroll 4
    for (int d2 = 0; d2 < 32; ++d2) {
        double2 a0 = *(const double2*)&xi0[2 * d2];
        double2 b0 = *(const double2*)&xj0[2 * d2];
        double2 a1 = *(const double2*)&xi1[2 * d2];
        double2 b1 = *(const double2*)&xj1[2 * d2];
        p0 = fma(a0.y, b0.y, fma(a0.x, b0.x, p0));
        p1 = fma(a1.y, b1.y, fma(a1.x, b1.x, p1));
    }
    double m = init;
#pragma unroll 8
    for (int c = 0; c < HH; ++c) {
        double2 wab = *(const double2*)&wpack[4 * c];        // a, b
        double2 wbw = *(const double2*)&wpack[4 * c + 2];    // beta, wd
        double tt = fma(p1, wab.y, fma(p0, wab.x, wbw.x));
        tt = fmax(tt, 0.0);
        m = fma(tt, wbw.y, m);
    }
    return m;
}

// k1: feats = relu(X@w1+b1)@w2+b2 (f64 accum); Xc (f64) and Xcf (f32) both written.
// 1 row/block (1536 blocks -> 2x the TLP of EROWS=2; this kernel is latency-bound).
// block 0 additionally packs the score-MLP weights (f64 + f32).
__global__ __launch_bounds__(128)
void edgefeat_kernel(const float* __restrict__ X,
                     const float* __restrict__ w1, const float* __restrict__ b1,
                     const float* __restrict__ w2, const float* __restrict__ b2,
                     const float* __restrict__ gatep,
                     const float* __restrict__ sm_w1, const float* __restrict__ sm_b1,
                     const float* __restrict__ sm_w2,
                     double* __restrict__ Xc, float* __restrict__ Xcf,
                     double* __restrict__ wpack, float4* __restrict__ wpackf) {
    __shared__ float  Xs[FF];
    __shared__ double Hs[HH];
    const int h = threadIdx.x;            // 0..127 output column
    const int row = blockIdx.x;           // global row in [0, B*N)
    Xs[h] = X[(size_t)row * FF + h];
    if (blockIdx.x == 0) {
        // wpack[c] = {w1[0,c], w1[1,c], b1[c], w2[c,1]-w2[c,0]}
        double a  = (double)sm_w1[h];
        double bq = (double)sm_w1[HH + h];
        double be = (double)sm_b1[h];
        double wd = (double)sm_w2[2 * h + 1] - (double)sm_w2[2 * h + 0];
        wpack[4 * h + 0] = a;  wpack[4 * h + 1] = bq;
        wpack[4 * h + 2] = be; wpack[4 * h + 3] = wd;
        wpackf[h] = make_float4((float)a, (float)bq, (float)be, (float)wd);
    }
    __syncthreads();
    double acc = (double)b1[h];
    for (int f = 0; f < FF; ++f)
        acc = fma((double)Xs[f], (double)w1[f * HH + h], acc);   // coalesced across h
    Hs[h] = acc > 0.0 ? acc : 0.0;
    __syncthreads();
    acc = (double)b2[h];
    for (int c = 0; c < HH; ++c)
        acc = fma(Hs[c], (double)w2[c * HH + h], acc);
    const double gate = (double)gatep[0];
    const int k = h & 1, d = h >> 1;
    const int b = row / NN;
    const int i = row % NN;
    double v = (double)Xs[h] + gate * acc;
    size_t idx = (((size_t)(b * 2 + k)) * NN + i) * 64 + d;
    Xc[idx]  = v;
    Xcf[idx] = (float)v;
}

// k2: 1024 threads per 32x32 tile. 4-way lane slicing (s = tid&3): each thread
// does 1/4 of the gram K-dim (4 b128 LDS reads/operand) and 1/4 of the MLP
// channels; 2-step __shfl_xor butterflies reduce. 8 waves/SIMD (32-wave/CU cap).
__global__ __launch_bounds__(1024, 8)
void edge_decide_kernel(const double* __restrict__ Xc,
                        const float* __restrict__ Xcf,
                        const double* __restrict__ wpack,
                        const float4* __restrict__ wpackf,
                        const float* __restrict__ sm_b2,
                        const float* __restrict__ gumbel,
                        float* __restrict__ out) {
    __shared__ float  Ai[2][TS][LST];  // 272B rows: 16B-aligned, banks <=2-way (free)
    __shared__ float  Aj[2][TS][LST];
    __shared__ float4 Wl[HH];          // packed score-MLP weights {a,b,beta,wd}
    __shared__ float  As[TS][TS + 1];
    const int b = blockIdx.y;
    const int t = blockIdx.x;
    // decode upper-triangular pair index: t -> (ti, tj), tj >= ti   (T=24)
    int ti = (int)((49.0 - sqrt(2401.0 - 8.0 * (double)t)) * 0.5);
    int base = ti * (49 - ti) / 2;
    if (t < base) { --ti; base = ti * (49 - ti) / 2; }
    else { int nb = (ti + 1) * (48 - ti) / 2; if (t >= nb) { ++ti; base = nb; } }
    const int tj = t - base + ti;
    const int tid = threadIdx.x;
    const int i0 = ti * TS, j0 = tj * TS;

    // stage f32 Xcf tiles (coalesced float2 global reads; 4 loads/thread)
    for (int q = 0; q < 2; ++q) {
        int flat = tid + 1024 * q;       // pair index over (k, r, dp)
        int dp = flat & 31;
        int r  = (flat >> 5) & 31;
        int k  = flat >> 10;
        size_t rowbase = ((size_t)(b * 2 + k)) * NN;
        *(float2*)&Ai[k][r][2 * dp] = *(const float2*)&Xcf[(rowbase + i0 + r) * 64 + 2 * dp];
        *(float2*)&Aj[k][r][2 * dp] = *(const float2*)&Xcf[(rowbase + j0 + r) * 64 + 2 * dp];
    }
    if (tid < HH) Wl[tid] = wpackf[tid];

    const int s  = tid & 3;          // slice within lane quad
    const int e  = tid >> 2;         // edge-quad id 0..255
    const int rh = e >> 4;           // 0..15 (wave-constant -> Ai reads broadcast)
    const int ch = e & 15;           // 0..15
    const int r0 = rh, r1 = rh + 16;
    const int c0 = 2 * ch, c1 = c0 + 1;
    const int gi0 = i0 + r0, gi1 = i0 + r1;
    const int gj0 = j0 + c0, gj1 = j0 + c1;

    // issue gumbel loads early (s==0 lanes only; hide global latency under gram)
    float4 g0v = make_float4(0.f, 0.f, 0.f, 0.f);
    float4 g1v = make_float4(0.f, 0.f, 0.f, 0.f);
    if (s == 0) {
        g0v = *(const float4*)&gumbel[(((size_t)b * NN + gi0) * NN + gj0) * 2];
        g1v = *(const float4*)&gumbel[(((size_t)b * NN + gi1) * NN + gj0) * 2];
    }
    __syncthreads();

    // f32 gram, 4-way K-sliced via b128 reads: slice s covers float4 idx s+4*it
    float p000 = 0.f, p001 = 0.f, p010 = 0.f, p011 = 0.f;
    float p100 = 0.f, p101 = 0.f, p110 = 0.f, p111 = 0.f;
#pragma unroll
    for (int it = 0; it < 4; ++it) {
        const int d4 = (s + 4 * it) * 4;    // float offset of the float4
        float4 a00 = *(const float4*)&Ai[0][r0][d4];
        float4 a01 = *(const float4*)&Ai[0][r1][d4];
        float4 a10 = *(const float4*)&Ai[1][r0][d4];
        float4 a11 = *(const float4*)&Ai[1][r1][d4];
        float4 b00 = *(const float4*)&Aj[0][c0][d4];
        float4 b01 = *(const float4*)&Aj[0][c1][d4];
        float4 b10 = *(const float4*)&Aj[1][c0][d4];
        float4 b11 = *(const float4*)&Aj[1][c1][d4];
        p000 = fmaf(a00.w, b00.w, fmaf(a00.z, b00.z, fmaf(a00.y, b00.y, fmaf(a00.x, b00.x, p000))));
        p001 = fmaf(a00.w, b01.w, fmaf(a00.z, b01.z, fmaf(a00.y, b01.y, fmaf(a00.x, b01.x, p001))));
        p010 = fmaf(a01.w, b00.w, fmaf(a01.z, b00.z, fmaf(a01.y, b00.y, fmaf(a01.x, b00.x, p010))));
        p011 = fmaf(a01.w, b01.w, fmaf(a01.z, b01.z, fmaf(a01.y, b01.y, fmaf(a01.x, b01.x, p011))));
        p100 = fmaf(a10.w, b10.w, fmaf(a10.z, b10.z, fmaf(a10.y, b10.y, fmaf(a10.x, b10.x, p100))));
        p101 = fmaf(a10.w, b11.w, fmaf(a10.z, b11.z, fmaf(a10.y, b11.y, fmaf(a10.x, b11.x, p101))));
        p110 = fmaf(a11.w, b10.w, fmaf(a11.z, b10.z, fmaf(a11.y, b10.y, fmaf(a11.x, b10.x, p110))));
        p111 = fmaf(a11.w, b11.w, fmaf(a11.z, b11.z, fmaf(a11.y, b11.y, fmaf(a11.x, b11.x, p111))));
    }
    // butterfly-reduce p over the lane quad; all 4 lanes get the full dots
    p000 += __shfl_xor(p000, 1); p000 += __shfl_xor(p000, 2);
    p001 += __shfl_xor(p001, 1); p001 += __shfl_xor(p001, 2);
    p010 += __shfl_xor(p010, 1); p010 += __shfl_xor(p010, 2);
    p011 += __shfl_xor(p011, 1); p011 += __shfl_xor(p011, 2);
    p100 += __shfl_xor(p100, 1); p100 += __shfl_xor(p100, 2);
    p101 += __shfl_xor(p101, 1); p101 += __shfl_xor(p101, 2);
    p110 += __shfl_xor(p110, 1); p110 += __shfl_xor(p110, 2);
    p111 += __shfl_xor(p111, 1); p111 += __shfl_xor(p111, 2);

    // f32 edge MLP, 4-way channel-sliced: slice s covers c = s + 4*it; weights via
    // LDS reads (4 unique 16B addrs/wave on disjoint banks -> conflict-free).
    float m00 = 0.f, m01 = 0.f, m10 = 0.f, m11 = 0.f;
#pragma unroll 8
    for (int it = 0; it < 32; ++it) {
        float4 w = Wl[s + 4 * it];     // {a, b, beta, wd}
        float tt;
        tt = fmaf(p100, w.y, fmaf(p000, w.x, w.z)); tt = fmaxf(tt, 0.f); m00 = fmaf(tt, w.w, m00);
        tt = fmaf(p101, w.y, fmaf(p001, w.x, w.z)); tt = fmaxf(tt, 0.f); m01 = fmaf(tt, w.w, m01);
        tt = fmaf(p110, w.y, fmaf(p010, w.x, w.z)); tt = fmaxf(tt, 0.f); m10 = fmaf(tt, w.w, m10);
        tt = fmaf(p111, w.y, fmaf(p011, w.x, w.z)); tt = fmaxf(tt, 0.f); m11 = fmaf(tt, w.w, m11);
    }
    m00 += __shfl_xor(m00, 1); m00 += __shfl_xor(m00, 2);
    m01 += __shfl_xor(m01, 1); m01 += __shfl_xor(m01, 2);
    m10 += __shfl_xor(m10, 1); m10 += __shfl_xor(m10, 2);
    m11 += __shfl_xor(m11, 1); m11 += __shfl_xor(m11, 2);

    if (s == 0) {
        const double bd = (double)sm_b2[1] - (double)sm_b2[0];
        double i00 = bd + ((double)g0v.y - (double)g0v.x);
        double i01 = bd + ((double)g0v.w - (double)g0v.z);
        double i10 = bd + ((double)g1v.y - (double)g1v.x);
        double i11 = bd + ((double)g1v.w - (double)g1v.z);
        float f00 = m00 + (float)i00;
        float f01 = m01 + (float)i01;
        float f10 = m10 + (float)i10;
        float f11 = m11 + (float)i11;
        float A00 = f00 > 0.f ? 1.f : 0.f;
        float A01 = f01 > 0.f ? 1.f : 0.f;
        float A10 = f10 > 0.f ? 1.f : 0.f;
        float A11 = f11 > 0.f ? 1.f : 0.f;
        float fm = fminf(fminf(fabsf(f00), fabsf(f01)), fminf(fabsf(f10), fabsf(f11)));
        if (__builtin_expect(fm < THR, 0)) {
            // rare: exact f64 re-decide (bit-identical to the original f64 kernel)
            if (fabsf(f00) < THR) A00 = edge_exact_f64(Xc, wpack, b, gi0, gj0, i00) > 0.0 ? 1.f : 0.f;
            if (fabsf(f01) < THR) A01 = edge_exact_f64(Xc, wpack, b, gi0, gj1, i01) > 0.0 ? 1.f : 0.f;
            if (fabsf(f10) < THR) A10 = edge_exact_f64(Xc, wpack, b, gi1, gj0, i10) > 0.0 ? 1.f : 0.f;
            if (fabsf(f11) < THR) A11 = edge_exact_f64(Xc, wpack, b, gi1, gj1, i11) > 0.0 ? 1.f : 0.f;
        }
        As[r0][c0] = A00; As[r0][c1] = A01;
        As[r1][c0] = A10; As[r1][c1] = A11;
    }
    __syncthreads();

    if (s == 0) {
        float A00 = As[r0][c0], A01 = As[r0][c1];
        float A10 = As[r1][c0], A11 = As[r1][c1];
        if (ti != tj) {
            // direct tile (i<j guaranteed)
            *(float2*)&out[((size_t)b * NN + gi0) * NN + gj0] = make_float2(A00, A01);
            *(float2*)&out[((size_t)b * NN + gi1) * NN + gj0] = make_float2(A10, A11);
            // transposed tile: out[b, j0+jr, i0+ic] = As[ic][jr]
            float2 t0 = make_float2(As[c0][r0], As[c1][r0]);
            *(float2*)&out[((size_t)b * NN + j0 + r0) * NN + i0 + c0] = t0;
            float2 t1 = make_float2(As[c0][r1], As[c1][r1]);
            *(float2*)&out[((size_t)b * NN + j0 + r1) * NN + i0 + c0] = t1;
        } else {
            // diagonal tile: upper value mirrored, diag = 0
            float v00 = (r0 < c0) ? A00 : ((r0 > c0) ? As[c0][r0] : 0.0f);
            float v01 = (r0 < c1) ? A01 : ((r0 > c1) ? As[c1][r0] : 0.0f);
            float v10 = (r1 < c0) ? A10 : ((r1 > c0) ? As[c0][r1] : 0.0f);
            float v11 = (r1 < c1) ? A11 : ((r1 > c1) ? As[c1][r1] : 0.0f);
            *(float2*)&out[((size_t)b * NN + gi0) * NN + gj0] = make_float2(v00, v01);
            *(float2*)&out[((size_t)b * NN + gi1) * NN + gj0] = make_float2(v10, v11);
        }
    }
}

extern "C" void kernel_launch(void* const* d_in, const int* in_sizes, int n_in,
                              void* d_out, int out_size, void* d_ws, size_t ws_size,
                              hipStream_t stream) {
    const float* X      = (const float*)d_in[0];
    const float* ef_w1  = (const float*)d_in[1];
    const float* ef_b1  = (const float*)d_in[2];
    const float* ef_w2  = (const float*)d_in[3];
    const float* ef_b2  = (const float*)d_in[4];
    const float* gate   = (const float*)d_in[5];
    const float* sm_w1  = (const float*)d_in[6];
    const float* sm_b1  = (const float*)d_in[7];
    const float* sm_w2  = (const float*)d_in[8];
    const float* sm_b2  = (const float*)d_in[9];
    const float* gumbel = (const float*)d_in[10];
    float* out = (float*)d_out;

    double* Xc     = (double*)d_ws;                         // 2*2*768*64 doubles = 1.5 MiB
    double* wpack  = Xc + (size_t)BB * 2 * NN * 64;         // 512 doubles
    float4* wpackf = (float4*)(wpack + 4 * HH);             // 128 float4
    float*  Xcf    = (float*)(wpackf + HH);                 // 768 KiB f32 copy

    edgefeat_kernel<<<BB * NN, 128, 0, stream>>>(
        X, ef_w1, ef_b1, ef_w2, ef_b2, gate, sm_w1, sm_b1, sm_w2, Xc, Xcf, wpack, wpackf);
    dim3 grid(NPAIR, BB);
    edge_decide_kernel<<<grid, 1024, 0, stream>>>(Xc, Xcf, wpack, wpackf, sm_b2, gumbel, out);
}

// Round 8
// 118.699 us; speedup vs baseline: 1.0741x; 1.0741x over previous
//
#include <hip/hip_runtime.h>

#define BB 2
#define NN 768
#define FF 128
#define HH 128
#define TS 32
#define LST 68                       // LDS row stride (floats): 272B rows, 16B-aligned, <=2-way banks
#define NT (NN / TS)                 // 24 tiles per dim
#define NPAIR (NT * (NT + 1) / 2)    // 300 upper-triangular tile pairs
#define EROWS 2
#define THR 4e-3f

// ---- exact f64 slow path: recompute gram from global Xc + f64 MLP --------
// Same values/fma order as the original always-f64 kernel; executed only in a
// cold branch (|m32| < THR, ~1e-4 of edges). Fully inlined: no call ABI/spills.
__device__ __forceinline__
double edge_exact_f64(const double* __restrict__ Xc, const double* __restrict__ wpack,
                      int b, int i, int j, double init) {
    const double* xi0 = Xc + ((size_t)(b * 2 + 0) * NN + i) * 64;
    const double* xj0 = Xc + ((size_t)(b * 2 + 0) * NN + j) * 64;
    const double* xi1 = Xc + ((size_t)(b * 2 + 1) * NN + i) * 64;
    const double* xj1 = Xc + ((size_t)(b * 2 + 1) * NN + j) * 64;
    double p0 = 0.0, p1 = 0.0;
#pragma unroll 4
    for (int d2 = 0; d2 < 32; ++d2) {
        double2 a0 = *(const double2*)&xi0[2 * d2];
        double2 b0 = *(const double2*)&xj0[2 * d2];
        double2 a1 = *(const double2*)&xi1[2 * d2];
        double2 b1 = *(const double2*)&xj1[2 * d2];
        p0 = fma(a0.y, b0.y, fma(a0.x, b0.x, p0));
        p1 = fma(a1.y, b1.y, fma(a1.x, b1.x, p1));
    }
    double m = init;
#pragma unroll 8
    for (int c = 0; c < HH; ++c) {
        double2 wab = *(const double2*)&wpack[4 * c];        // a, b
        double2 wbw = *(const double2*)&wpack[4 * c + 2];    // beta, wd
        double tt = fma(p1, wab.y, fma(p0, wab.x, wbw.x));
        tt = fmax(tt, 0.0);
        m = fma(tt, wbw.y, m);
    }
    return m;
}

// k1: feats = relu(X@w1+b1)@w2+b2 (f64 accum); Xc (f64) and Xcf (f32) both written.
// block 0 additionally packs the score-MLP weights (f64 + f32).
__global__ __launch_bounds__(128)
void edgefeat_kernel(const float* __restrict__ X,
                     const float* __restrict__ w1, const float* __restrict__ b1,
                     const float* __restrict__ w2, const float* __restrict__ b2,
                     const float* __restrict__ gatep,
                     const float* __restrict__ sm_w1, const float* __restrict__ sm_b1,
                     const float* __restrict__ sm_w2,
                     double* __restrict__ Xc, float* __restrict__ Xcf,
                     double* __restrict__ wpack, float4* __restrict__ wpackf) {
    __shared__ float  Xs[EROWS][FF];
    __shared__ double Hs[EROWS][HH];
    const int h = threadIdx.x;            // 0..127 output column
    const int row0 = blockIdx.x * EROWS;  // global row in [0, B*N)
    for (int r = 0; r < EROWS; ++r) Xs[r][h] = X[(size_t)(row0 + r) * FF + h];
    if (blockIdx.x == 0) {
        // wpack[c] = {w1[0,c], w1[1,c], b1[c], w2[c,1]-w2[c,0]}
        double a  = (double)sm_w1[h];
        double bq = (double)sm_w1[HH + h];
        double be = (double)sm_b1[h];
        double wd = (double)sm_w2[2 * h + 1] - (double)sm_w2[2 * h + 0];
        wpack[4 * h + 0] = a;  wpack[4 * h + 1] = bq;
        wpack[4 * h + 2] = be; wpack[4 * h + 3] = wd;
        wpackf[h] = make_float4((float)a, (float)bq, (float)be, (float)wd);
    }
    __syncthreads();
    double acc[EROWS];
    double bb = (double)b1[h];
    for (int r = 0; r < EROWS; ++r) acc[r] = bb;
    for (int f = 0; f < FF; ++f) {
        double w = (double)w1[f * HH + h];        // coalesced across h
        for (int r = 0; r < EROWS; ++r) acc[r] = fma((double)Xs[r][f], w, acc[r]);
    }
    for (int r = 0; r < EROWS; ++r) Hs[r][h] = acc[r] > 0.0 ? acc[r] : 0.0;
    __syncthreads();
    bb = (double)b2[h];
    for (int r = 0; r < EROWS; ++r) acc[r] = bb;
    for (int c = 0; c < HH; ++c) {
        double w = (double)w2[c * HH + h];
        for (int r = 0; r < EROWS; ++r) acc[r] = fma(Hs[r][c], w, acc[r]);
    }
    const double gate = (double)gatep[0];
    const int k = h & 1, d = h >> 1;
    const int b = row0 / NN;
    const int i0 = row0 % NN;
    for (int r = 0; r < EROWS; ++r) {
        double v = (double)Xs[r][h] + gate * acc[r];
        size_t idx = (((size_t)(b * 2 + k)) * NN + (i0 + r)) * 64 + d;
        Xc[idx]  = v;
        Xcf[idx] = (float)v;
    }
}

// k2: 512 threads per 32x32 tile. Lane-pair slicing (s = tid&1) on the gram
// K-dim (b128 LDS reads, __shfl_xor reduce), then EDGE-sliced MLP: lane s owns
// its row's 2 edges over ALL 128 channels -> channel index is wave-uniform ->
// weights come via batched scalar loads (s_load), zero LDS in the MLP phase.
__global__ __launch_bounds__(512, 6)
void edge_decide_kernel(const double* __restrict__ Xc,
                        const float* __restrict__ Xcf,
                        const double* __restrict__ wpack,
                        const float4* __restrict__ wpackf,
                        const float* __restrict__ sm_b2,
                        const float* __restrict__ gumbel,
                        float* __restrict__ out) {
    __shared__ float  Ai[2][TS][LST];  // 272B rows: 16B-aligned, banks <=2-way (free)
    __shared__ float  Aj[2][TS][LST];
    __shared__ float  As[TS][TS + 1];
    const int b = blockIdx.y;
    const int t = blockIdx.x;
    // decode upper-triangular pair index: t -> (ti, tj), tj >= ti   (T=24)
    int ti = (int)((49.0 - sqrt(2401.0 - 8.0 * (double)t)) * 0.5);
    int base = ti * (49 - ti) / 2;
    if (t < base) { --ti; base = ti * (49 - ti) / 2; }
    else { int nb = (ti + 1) * (48 - ti) / 2; if (t >= nb) { ++ti; base = nb; } }
    const int tj = t - base + ti;
    const int tid = threadIdx.x;
    const int i0 = ti * TS, j0 = tj * TS;

    // stage f32 Xcf tiles (coalesced float2 global reads)
    for (int q = 0; q < 4; ++q) {
        int flat = tid + 512 * q;        // pair index over (k, r, dp)
        int dp = flat & 31;
        int r  = (flat >> 5) & 31;
        int k  = flat >> 10;
        size_t rowbase = ((size_t)(b * 2 + k)) * NN;
        *(float2*)&Ai[k][r][2 * dp] = *(const float2*)&Xcf[(rowbase + i0 + r) * 64 + 2 * dp];
        *(float2*)&Aj[k][r][2 * dp] = *(const float2*)&Xcf[(rowbase + j0 + r) * 64 + 2 * dp];
    }

    const int s  = tid & 1;          // slice within lane pair
    const int e  = tid >> 1;         // edge-quad id 0..255
    const int rh = e >> 4;           // 0..15
    const int ch = e & 15;           // 0..15
    const int r0 = rh, r1 = rh + 16;
    const int c0 = 2 * ch, c1 = c0 + 1;
    const int lr  = (s == 0) ? r0 : r1;     // lane-owned local row
    const int gr  = i0 + lr;                // lane-owned global row
    const int gj0 = j0 + c0, gj1 = j0 + c1;

    // per-lane gumbel load for the owned row (issued early, hidden under gram)
    float4 gv = *(const float4*)&gumbel[(((size_t)b * NN + gr) * NN + gj0) * 2];
    __syncthreads();

    // f32 gram, K-sliced via b128 reads: slice s covers float4 idx s+2*it
    float p000 = 0.f, p001 = 0.f, p010 = 0.f, p011 = 0.f;
    float p100 = 0.f, p101 = 0.f, p110 = 0.f, p111 = 0.f;
#pragma unroll
    for (int it = 0; it < 8; ++it) {
        const int d4 = (s + 2 * it) * 4;    // float offset of the float4
        float4 a00 = *(const float4*)&Ai[0][r0][d4];
        float4 a01 = *(const float4*)&Ai[0][r1][d4];
        float4 a10 = *(const float4*)&Ai[1][r0][d4];
        float4 a11 = *(const float4*)&Ai[1][r1][d4];
        float4 b00 = *(const float4*)&Aj[0][c0][d4];
        float4 b01 = *(const float4*)&Aj[0][c1][d4];
        float4 b10 = *(const float4*)&Aj[1][c0][d4];
        float4 b11 = *(const float4*)&Aj[1][c1][d4];
        p000 = fmaf(a00.w, b00.w, fmaf(a00.z, b00.z, fmaf(a00.y, b00.y, fmaf(a00.x, b00.x, p000))));
        p001 = fmaf(a00.w, b01.w, fmaf(a00.z, b01.z, fmaf(a00.y, b01.y, fmaf(a00.x, b01.x, p001))));
        p010 = fmaf(a01.w, b00.w, fmaf(a01.z, b00.z, fmaf(a01.y, b00.y, fmaf(a01.x, b00.x, p010))));
        p011 = fmaf(a01.w, b01.w, fmaf(a01.z, b01.z, fmaf(a01.y, b01.y, fmaf(a01.x, b01.x, p011))));
        p100 = fmaf(a10.w, b10.w, fmaf(a10.z, b10.z, fmaf(a10.y, b10.y, fmaf(a10.x, b10.x, p100))));
        p101 = fmaf(a10.w, b11.w, fmaf(a10.z, b11.z, fmaf(a10.y, b11.y, fmaf(a10.x, b11.x, p101))));
        p110 = fmaf(a11.w, b10.w, fmaf(a11.z, b10.z, fmaf(a11.y, b10.y, fmaf(a11.x, b10.x, p110))));
        p111 = fmaf(a11.w, b11.w, fmaf(a11.z, b11.z, fmaf(a11.y, b11.y, fmaf(a11.x, b11.x, p111))));
    }
    // butterfly-reduce p over the lane pair; both lanes get the full dots
    p000 += __shfl_xor(p000, 1); p001 += __shfl_xor(p001, 1);
    p010 += __shfl_xor(p010, 1); p011 += __shfl_xor(p011, 1);
    p100 += __shfl_xor(p100, 1); p101 += __shfl_xor(p101, 1);
    p110 += __shfl_xor(p110, 1); p111 += __shfl_xor(p111, 1);

    // lane-owned edges: (lr, c0) and (lr, c1)
    const float pa0 = (s == 0) ? p000 : p010;   // k0, col c0
    const float pa1 = (s == 0) ? p100 : p110;   // k1, col c0
    const float pb0 = (s == 0) ? p001 : p011;   // k0, col c1
    const float pb1 = (s == 0) ? p101 : p111;   // k1, col c1

    // f32 edge MLP over all 128 channels; weights via batched uniform scalar
    // loads (8 x s_load dwordx4 per group) — zero LDS/VMEM pressure.
    float ma = 0.f, mb = 0.f;
#pragma unroll 1
    for (int c = 0; c < HH; c += 8) {
        float4 w[8];
#pragma unroll
        for (int u = 0; u < 8; ++u) w[u] = wpackf[c + u];
#pragma unroll
        for (int u = 0; u < 8; ++u) {
            float tt;
            tt = fmaf(pa1, w[u].y, fmaf(pa0, w[u].x, w[u].z)); tt = fmaxf(tt, 0.f); ma = fmaf(tt, w[u].w, ma);
            tt = fmaf(pb1, w[u].y, fmaf(pb0, w[u].x, w[u].z)); tt = fmaxf(tt, 0.f); mb = fmaf(tt, w[u].w, mb);
        }
    }

    // decision per lane (2 edges), rare exact-f64 re-decide
    const double bd = (double)sm_b2[1] - (double)sm_b2[0];
    double ia = bd + ((double)gv.y - (double)gv.x);
    double ib = bd + ((double)gv.w - (double)gv.z);
    float fa = ma + (float)ia;
    float fb = mb + (float)ib;
    float Aa = fa > 0.f ? 1.f : 0.f;
    float Ab = fb > 0.f ? 1.f : 0.f;
    if (__builtin_expect(fminf(fabsf(fa), fabsf(fb)) < THR, 0)) {
        if (fabsf(fa) < THR) Aa = edge_exact_f64(Xc, wpack, b, gr, gj0, ia) > 0.0 ? 1.f : 0.f;
        if (fabsf(fb) < THR) Ab = edge_exact_f64(Xc, wpack, b, gr, gj1, ib) > 0.0 ? 1.f : 0.f;
    }
    As[lr][c0] = Aa; As[lr][c1] = Ab;
    __syncthreads();

    if (ti != tj) {
        // direct tile: each lane writes its own row pair (i<j guaranteed)
        *(float2*)&out[((size_t)b * NN + gr) * NN + gj0] = make_float2(Aa, Ab);
        // transposed tile: row j0+lr, cols i0+c0..c1
        float2 tv = make_float2(As[c0][lr], As[c1][lr]);
        *(float2*)&out[((size_t)b * NN + j0 + lr) * NN + i0 + c0] = tv;
    } else {
        // diagonal tile: upper value mirrored, diag = 0
        float v0 = (lr < c0) ? Aa : ((lr > c0) ? As[c0][lr] : 0.0f);
        float v1 = (lr < c1) ? Ab : ((lr > c1) ? As[c1][lr] : 0.0f);
        *(float2*)&out[((size_t)b * NN + gr) * NN + gj0] = make_float2(v0, v1);
    }
}

extern "C" void kernel_launch(void* const* d_in, const int* in_sizes, int n_in,
                              void* d_out, int out_size, void* d_ws, size_t ws_size,
                              hipStream_t stream) {
    const float* X      = (const float*)d_in[0];
    const float* ef_w1  = (const float*)d_in[1];
    const float* ef_b1  = (const float*)d_in[2];
    const float* ef_w2  = (const float*)d_in[3];
    const float* ef_b2  = (const float*)d_in[4];
    const float* gate   = (const float*)d_in[5];
    const float* sm_w1  = (const float*)d_in[6];
    const float* sm_b1  = (const float*)d_in[7];
    const float* sm_w2  = (const float*)d_in[8];
    const float* sm_b2  = (const float*)d_in[9];
    const float* gumbel = (const float*)d_in[10];
    float* out = (float*)d_out;

    double* Xc     = (double*)d_ws;                         // 2*2*768*64 doubles = 1.5 MiB
    double* wpack  = Xc + (size_t)BB * 2 * NN * 64;         // 512 doubles
    float4* wpackf = (float4*)(wpack + 4 * HH);             // 128 float4
    float*  Xcf    = (float*)(wpackf + HH);                 // 768 KiB f32 copy

    edgefeat_kernel<<<BB * NN / EROWS, 128, 0, stream>>>(
        X, ef_w1, ef_b1, ef_w2, ef_b2, gate, sm_w1, sm_b1, sm_w2, Xc, Xcf, wpack, wpackf);
    dim3 grid(NPAIR, BB);
    edge_decide_kernel<<<grid, 512, 0, stream>>>(Xc, Xcf, wpack, wpackf, sm_b2, gumbel, out);
}

// Round 9
// 116.765 us; speedup vs baseline: 1.0919x; 1.0166x over previous
//
#include <hip/hip_runtime.h>

#define BB 2
#define NN 768
#define FF 128
#define HH 128
#define TS 32
#define LST 68                       // LDS row stride (floats): 272B rows, 16B-aligned, <=2-way banks
#define NT (NN / TS)                 // 24 tiles per dim
#define NPAIR (NT * (NT + 1) / 2)    // 300 upper-triangular tile pairs
#define EROWS 2
#define THR 4e-3f

// ---- exact f64 slow path: recompute gram from global Xc + f64 MLP --------
// Same math as the always-f64 baseline; executed only in a cold branch
// (|m32| < THR, ~1e-4 of edges). Fully inlined: no call ABI/spills.
__device__ __forceinline__
double edge_exact_f64(const double* __restrict__ Xc, const double* __restrict__ wpack,
                      int b, int i, int j, double init) {
    const double* xi0 = Xc + ((size_t)(b * 2 + 0) * NN + i) * 64;
    const double* xj0 = Xc + ((size_t)(b * 2 + 0) * NN + j) * 64;
    const double* xi1 = Xc + ((size_t)(b * 2 + 1) * NN + i) * 64;
    const double* xj1 = Xc + ((size_t)(b * 2 + 1) * NN + j) * 64;
    double p0 = 0.0, p1 = 0.0;
#pragma unroll 4
    for (int d2 = 0; d2 < 32; ++d2) {
        double2 a0 = *(const double2*)&xi0[2 * d2];
        double2 b0 = *(const double2*)&xj0[2 * d2];
        double2 a1 = *(const double2*)&xi1[2 * d2];
        double2 b1 = *(const double2*)&xj1[2 * d2];
        p0 = fma(a0.y, b0.y, fma(a0.x, b0.x, p0));
        p1 = fma(a1.y, b1.y, fma(a1.x, b1.x, p1));
    }
    double m = init;
#pragma unroll 8
    for (int c = 0; c < HH; ++c) {
        double2 wab = *(const double2*)&wpack[4 * c];        // a, b
        double2 wbw = *(const double2*)&wpack[4 * c + 2];    // beta, wd
        double tt = fma(p1, wab.y, fma(p0, wab.x, wbw.x));
        tt = fmax(tt, 0.0);
        m = fma(tt, wbw.y, m);
    }
    return m;
}

// k1: feats = relu(X@w1+b1)@w2+b2 (f64 accum, split-K x2); Xc (f64) + Xcf (f32).
// 256 threads: h = tid&127 (output col), kh = tid>>7 (K-half). Each layer's
// 128-deep dependent f64 chain becomes 64-deep; partials combined via LDS
// (deterministic order). Waves/SIMD: 1.5 -> 3. block 0 packs score-MLP weights.
__global__ __launch_bounds__(256)
void edgefeat_kernel(const float* __restrict__ X,
                     const float* __restrict__ w1, const float* __restrict__ b1,
                     const float* __restrict__ w2, const float* __restrict__ b2,
                     const float* __restrict__ gatep,
                     const float* __restrict__ sm_w1, const float* __restrict__ sm_b1,
                     const float* __restrict__ sm_w2,
                     double* __restrict__ Xc, float* __restrict__ Xcf,
                     double* __restrict__ wpack, float4* __restrict__ wpackf) {
    __shared__ float  Xs[EROWS][FF];
    __shared__ double Hp[2][EROWS][HH];   // per-K-half partials (reused for layer 2)
    __shared__ double Hs[EROWS][HH];      // relu'd hidden
    const int tid = threadIdx.x;
    const int h  = tid & 127;             // output column
    const int kh = tid >> 7;              // K-half 0/1
    const int row0 = blockIdx.x * EROWS;  // global row in [0, B*N)
    Xs[kh][h] = X[(size_t)(row0 + kh) * FF + h];   // 256 threads stage 2 rows
    if (blockIdx.x == 0 && kh == 0) {
        // wpack[c] = {w1[0,c], w1[1,c], b1[c], w2[c,1]-w2[c,0]}
        double a  = (double)sm_w1[h];
        double bq = (double)sm_w1[HH + h];
        double be = (double)sm_b1[h];
        double wd = (double)sm_w2[2 * h + 1] - (double)sm_w2[2 * h + 0];
        wpack[4 * h + 0] = a;  wpack[4 * h + 1] = bq;
        wpack[4 * h + 2] = be; wpack[4 * h + 3] = wd;
        wpackf[h] = make_float4((float)a, (float)bq, (float)be, (float)wd);
    }
    __syncthreads();
    const int f0 = kh * 64;
    // layer 1, K-half kh
    double acc0 = (kh == 0) ? (double)b1[h] : 0.0;
    double acc1 = acc0;
    for (int f = f0; f < f0 + 64; ++f) {
        double w = (double)w1[f * HH + h];        // coalesced across h
        acc0 = fma((double)Xs[0][f], w, acc0);
        acc1 = fma((double)Xs[1][f], w, acc1);
    }
    Hp[kh][0][h] = acc0; Hp[kh][1][h] = acc1;
    __syncthreads();
    if (kh == 0) {
        double v0 = Hp[0][0][h] + Hp[1][0][h];
        double v1 = Hp[0][1][h] + Hp[1][1][h];
        Hs[0][h] = v0 > 0.0 ? v0 : 0.0;
        Hs[1][h] = v1 > 0.0 ? v1 : 0.0;
    }
    __syncthreads();
    // layer 2, K-half kh
    acc0 = (kh == 0) ? (double)b2[h] : 0.0;
    acc1 = acc0;
    for (int c = f0; c < f0 + 64; ++c) {
        double w = (double)w2[c * HH + h];
        acc0 = fma(Hs[0][c], w, acc0);
        acc1 = fma(Hs[1][c], w, acc1);
    }
    Hp[kh][0][h] = acc0; Hp[kh][1][h] = acc1;
    __syncthreads();
    if (kh == 0) {
        const double gate = (double)gatep[0];
        const int k = h & 1, d = h >> 1;
        const int b = row0 / NN;
        const int i0 = row0 % NN;
#pragma unroll
        for (int r = 0; r < EROWS; ++r) {
            double a = Hp[0][r][h] + Hp[1][r][h];
            double v = (double)Xs[r][h] + gate * a;
            size_t idx = (((size_t)(b * 2 + k)) * NN + (i0 + r)) * 64 + d;
            Xc[idx]  = v;
            Xcf[idx] = (float)v;
        }
    }
}

// k2: 512 threads per 32x32 tile. Lane-pair slicing (s = tid&1) on the gram
// K-dim (b128 LDS reads, __shfl_xor reduce); EDGE-sliced MLP with
// double-buffered batched scalar weight loads (wA/wB static names — no
// runtime indexing) so s_load latency overlaps compute.
__global__ __launch_bounds__(512, 6)
void edge_decide_kernel(const double* __restrict__ Xc,
                        const float* __restrict__ Xcf,
                        const double* __restrict__ wpack,
                        const float4* __restrict__ wpackf,
                        const float* __restrict__ sm_b2,
                        const float* __restrict__ gumbel,
                        float* __restrict__ out) {
    __shared__ float  Ai[2][TS][LST];  // 272B rows: 16B-aligned, banks <=2-way (free)
    __shared__ float  Aj[2][TS][LST];
    __shared__ float  As[TS][TS + 1];
    const int b = blockIdx.y;
    const int t = blockIdx.x;
    // decode upper-triangular pair index: t -> (ti, tj), tj >= ti   (T=24)
    int ti = (int)((49.0 - sqrt(2401.0 - 8.0 * (double)t)) * 0.5);
    int base = ti * (49 - ti) / 2;
    if (t < base) { --ti; base = ti * (49 - ti) / 2; }
    else { int nb = (ti + 1) * (48 - ti) / 2; if (t >= nb) { ++ti; base = nb; } }
    const int tj = t - base + ti;
    const int tid = threadIdx.x;
    const int i0 = ti * TS, j0 = tj * TS;

    // stage f32 Xcf tiles (coalesced float4 global reads; 4 loads/thread)
    for (int q = 0; q < 2; ++q) {
        int flat = tid + 512 * q;        // index over (k, r, d4)
        int d4 = flat & 15;              // float4 slot within row (16/row)
        int r  = (flat >> 4) & 31;
        int k  = flat >> 9;
        size_t rowbase = ((size_t)(b * 2 + k)) * NN;
        *(float4*)&Ai[k][r][4 * d4] = *(const float4*)&Xcf[(rowbase + i0 + r) * 64 + 4 * d4];
        *(float4*)&Aj[k][r][4 * d4] = *(const float4*)&Xcf[(rowbase + j0 + r) * 64 + 4 * d4];
    }

    const int s  = tid & 1;          // slice within lane pair
    const int e  = tid >> 1;         // edge-quad id 0..255
    const int rh = e >> 4;           // 0..15
    const int ch = e & 15;           // 0..15
    const int r0 = rh, r1 = rh + 16;
    const int c0 = 2 * ch, c1 = c0 + 1;
    const int lr  = (s == 0) ? r0 : r1;     // lane-owned local row
    const int gr  = i0 + lr;                // lane-owned global row
    const int gj0 = j0 + c0, gj1 = j0 + c1;

    // per-lane gumbel load for the owned row (issued early, hidden under gram)
    float4 gv = *(const float4*)&gumbel[(((size_t)b * NN + gr) * NN + gj0) * 2];
    __syncthreads();

    // f32 gram, K-sliced via b128 reads: slice s covers float4 idx s+2*it
    float p000 = 0.f, p001 = 0.f, p010 = 0.f, p011 = 0.f;
    float p100 = 0.f, p101 = 0.f, p110 = 0.f, p111 = 0.f;
#pragma unroll
    for (int it = 0; it < 8; ++it) {
        const int d4 = (s + 2 * it) * 4;    // float offset of the float4
        float4 a00 = *(const float4*)&Ai[0][r0][d4];
        float4 a01 = *(const float4*)&Ai[0][r1][d4];
        float4 a10 = *(const float4*)&Ai[1][r0][d4];
        float4 a11 = *(const float4*)&Ai[1][r1][d4];
        float4 b00 = *(const float4*)&Aj[0][c0][d4];
        float4 b01 = *(const float4*)&Aj[0][c1][d4];
        float4 b10 = *(const float4*)&Aj[1][c0][d4];
        float4 b11 = *(const float4*)&Aj[1][c1][d4];
        p000 = fmaf(a00.w, b00.w, fmaf(a00.z, b00.z, fmaf(a00.y, b00.y, fmaf(a00.x, b00.x, p000))));
        p001 = fmaf(a00.w, b01.w, fmaf(a00.z, b01.z, fmaf(a00.y, b01.y, fmaf(a00.x, b01.x, p001))));
        p010 = fmaf(a01.w, b00.w, fmaf(a01.z, b00.z, fmaf(a01.y, b00.y, fmaf(a01.x, b00.x, p010))));
        p011 = fmaf(a01.w, b01.w, fmaf(a01.z, b01.z, fmaf(a01.y, b01.y, fmaf(a01.x, b01.x, p011))));
        p100 = fmaf(a10.w, b10.w, fmaf(a10.z, b10.z, fmaf(a10.y, b10.y, fmaf(a10.x, b10.x, p100))));
        p101 = fmaf(a10.w, b11.w, fmaf(a10.z, b11.z, fmaf(a10.y, b11.y, fmaf(a10.x, b11.x, p101))));
        p110 = fmaf(a11.w, b10.w, fmaf(a11.z, b10.z, fmaf(a11.y, b10.y, fmaf(a11.x, b10.x, p110))));
        p111 = fmaf(a11.w, b11.w, fmaf(a11.z, b11.z, fmaf(a11.y, b11.y, fmaf(a11.x, b11.x, p111))));
    }
    // butterfly-reduce p over the lane pair; both lanes get the full dots
    p000 += __shfl_xor(p000, 1); p001 += __shfl_xor(p001, 1);
    p010 += __shfl_xor(p010, 1); p011 += __shfl_xor(p011, 1);
    p100 += __shfl_xor(p100, 1); p101 += __shfl_xor(p101, 1);
    p110 += __shfl_xor(p110, 1); p111 += __shfl_xor(p111, 1);

    // lane-owned edges: (lr, c0) and (lr, c1)
    const float pa0 = (s == 0) ? p000 : p010;   // k0, col c0
    const float pa1 = (s == 0) ? p100 : p110;   // k1, col c0
    const float pb0 = (s == 0) ? p001 : p011;   // k0, col c1
    const float pb1 = (s == 0) ? p101 : p111;   // k1, col c1

    // f32 edge MLP over 128 channels; weights via batched uniform scalar loads,
    // double-buffered (wA/wB) so each group's s_loads overlap prior compute.
    float ma = 0.f, mb = 0.f;
    float4 wA[8], wB[8];
#pragma unroll
    for (int u = 0; u < 8; ++u) wA[u] = wpackf[u];
#pragma unroll 1
    for (int cg = 0; cg < 8; ++cg) {
        const float4* nxt1 = wpackf + (16 * cg + 8);
#pragma unroll
        for (int u = 0; u < 8; ++u) wB[u] = nxt1[u];
#pragma unroll
        for (int u = 0; u < 8; ++u) {
            float tt;
            tt = fmaf(pa1, wA[u].y, fmaf(pa0, wA[u].x, wA[u].z)); tt = fmaxf(tt, 0.f); ma = fmaf(tt, wA[u].w, ma);
            tt = fmaf(pb1, wA[u].y, fmaf(pb0, wA[u].x, wA[u].z)); tt = fmaxf(tt, 0.f); mb = fmaf(tt, wA[u].w, mb);
        }
        const float4* nxt2 = wpackf + ((cg < 7) ? (16 * cg + 16) : 0);
#pragma unroll
        for (int u = 0; u < 8; ++u) wA[u] = nxt2[u];
#pragma unroll
        for (int u = 0; u < 8; ++u) {
            float tt;
            tt = fmaf(pa1, wB[u].y, fmaf(pa0, wB[u].x, wB[u].z)); tt = fmaxf(tt, 0.f); ma = fmaf(tt, wB[u].w, ma);
            tt = fmaf(pb1, wB[u].y, fmaf(pb0, wB[u].x, wB[u].z)); tt = fmaxf(tt, 0.f); mb = fmaf(tt, wB[u].w, mb);
        }
    }

    // decision per lane (2 edges), rare exact-f64 re-decide
    const double bd = (double)sm_b2[1] - (double)sm_b2[0];
    double ia = bd + ((double)gv.y - (double)gv.x);
    double ib = bd + ((double)gv.w - (double)gv.z);
    float fa = ma + (float)ia;
    float fb = mb + (float)ib;
    float Aa = fa > 0.f ? 1.f : 0.f;
    float Ab = fb > 0.f ? 1.f : 0.f;
    if (__builtin_expect(fminf(fabsf(fa), fabsf(fb)) < THR, 0)) {
        if (fabsf(fa) < THR) Aa = edge_exact_f64(Xc, wpack, b, gr, gj0, ia) > 0.0 ? 1.f : 0.f;
        if (fabsf(fb) < THR) Ab = edge_exact_f64(Xc, wpack, b, gr, gj1, ib) > 0.0 ? 1.f : 0.f;
    }
    As[lr][c0] = Aa; As[lr][c1] = Ab;
    __syncthreads();

    if (ti != tj) {
        // direct tile: each lane writes its own row pair (i<j guaranteed)
        *(float2*)&out[((size_t)b * NN + gr) * NN + gj0] = make_float2(Aa, Ab);
        // transposed tile: row j0+lr, cols i0+c0..c1
        float2 tv = make_float2(As[c0][lr], As[c1][lr]);
        *(float2*)&out[((size_t)b * NN + j0 + lr) * NN + i0 + c0] = tv;
    } else {
        // diagonal tile: upper value mirrored, diag = 0
        float v0 = (lr < c0) ? Aa : ((lr > c0) ? As[c0][lr] : 0.0f);
        float v1 = (lr < c1) ? Ab : ((lr > c1) ? As[c1][lr] : 0.0f);
        *(float2*)&out[((size_t)b * NN + gr) * NN + gj0] = make_float2(v0, v1);
    }
}

extern "C" void kernel_launch(void* const* d_in, const int* in_sizes, int n_in,
                              void* d_out, int out_size, void* d_ws, size_t ws_size,
                              hipStream_t stream) {
    const float* X      = (const float*)d_in[0];
    const float* ef_w1  = (const float*)d_in[1];
    const float* ef_b1  = (const float*)d_in[2];
    const float* ef_w2  = (const float*)d_in[3];
    const float* ef_b2  = (const float*)d_in[4];
    const float* gate   = (const float*)d_in[5];
    const float* sm_w1  = (const float*)d_in[6];
    const float* sm_b1  = (const float*)d_in[7];
    const float* sm_w2  = (const float*)d_in[8];
    const float* sm_b2  = (const float*)d_in[9];
    const float* gumbel = (const float*)d_in[10];
    float* out = (float*)d_out;

    double* Xc     = (double*)d_ws;                         // 2*2*768*64 doubles = 1.5 MiB
    double* wpack  = Xc + (size_t)BB * 2 * NN * 64;         // 512 doubles
    float4* wpackf = (float4*)(wpack + 4 * HH);             // 128 float4
    float*  Xcf    = (float*)(wpackf + HH);                 // 768 KiB f32 copy

    edgefeat_kernel<<<BB * NN / EROWS, 256, 0, stream>>>(
        X, ef_w1, ef_b1, ef_w2, ef_b2, gate, sm_w1, sm_b1, sm_w2, Xc, Xcf, wpack, wpackf);
    dim3 grid(NPAIR, BB);
    edge_decide_kernel<<<grid, 512, 0, stream>>>(Xc, Xcf, wpack, wpackf, sm_b2, gumbel, out);
}